// Round 2
// baseline (4023.583 us; speedup 1.0000x reference)
//
#include <hip/hip_runtime.h>
#include <math.h>

#define CCH 512
#define HW 4096
#define NN 32768
#define NE 8192

// ws layout (bytes)
#define WS_BT  0                        // Bt: [512][8192] f32 = 16777216
#define WS_ZZ  (16777216)               // zz f32 [32768] (np-pairwise-replicated)
#define WS_IDX (WS_ZZ + 131072)         // argmin idx [32768] i32
#define WS_ACC (WS_IDX + 131072)        // accs[0]=loss num (f64), accs[1]=wsum (f64)

#define AS 68
#define BS 132

// ---------------- K0: transpose codebook [8192,512] -> Bt [512,8192]; zero accumulators
__global__ __launch_bounds__(256) void k_transpose(const float* __restrict__ cb,
                                                   float* __restrict__ Bt,
                                                   double* __restrict__ accs) {
    __shared__ float S[32 * 33];
    int tid = threadIdx.x;
    int lane = tid & 31, r8 = tid >> 5;
    int bj = blockIdx.x & 255, bc = blockIdx.x >> 8;
    int j0 = bj * 32, c0 = bc * 32;
    if (blockIdx.x == 0 && tid == 0) { accs[0] = 0.0; accs[1] = 0.0; }
#pragma unroll
    for (int rr = 0; rr < 4; ++rr) {
        int r = r8 + rr * 8;
        S[r * 33 + lane] = cb[(size_t)(j0 + r) * CCH + c0 + lane];
    }
    __syncthreads();
#pragma unroll
    for (int rr = 0; rr < 4; ++rr) {
        int r = r8 + rr * 8;
        Bt[(size_t)(c0 + r) * NE + j0 + lane] = S[lane * 33 + r];
    }
}

// ---------------- K1: zz[n] = np.sum(zf*zf, axis=1) with numpy's EXACT pairwise tree.
// pairwise(512) = (B0+B1)+(B2+B3); each 128-block: 8 stride-8 accumulators,
// ((r0+r1)+(r2+r3))+((r4+r5)+(r6+r7)). __fmul_rn/__fadd_rn forbid contraction.
__global__ __launch_bounds__(256) void k_zz(const float* __restrict__ z,
                                            float* __restrict__ zz) {
    int t = threadIdx.x;
    int n = blockIdx.x * 256 + t;
    int b = n >> 12, hw = n & 4095;
    const float* zp = z + (size_t)b * CCH * HW + hw;
    float blk[4];
#pragma unroll
    for (int q = 0; q < 4; ++q) {
        float r[8];
#pragma unroll
        for (int j = 0; j < 8; ++j) {
            float v = zp[(size_t)(q * 128 + j) * HW];
            r[j] = __fmul_rn(v, v);
        }
        for (int i = 8; i < 128; i += 8) {
#pragma unroll
            for (int j = 0; j < 8; ++j) {
                float v = zp[(size_t)(q * 128 + i + j) * HW];
                r[j] = __fadd_rn(r[j], __fmul_rn(v, v));
            }
        }
        blk[q] = __fadd_rn(__fadd_rn(__fadd_rn(r[0], r[1]), __fadd_rn(r[2], r[3])),
                           __fadd_rn(__fadd_rn(r[4], r[5]), __fadd_rn(r[6], r[7])));
    }
    zz[n] = __fadd_rn(__fadd_rn(blk[0], blk[1]), __fadd_rn(blk[2], blk[3]));
}

// ---------------- K2: wsum = sum(m==0)
__global__ __launch_bounds__(256) void k_wsum(const float* __restrict__ m,
                                              double* __restrict__ accs) {
    __shared__ int sc[4];
    int tid = threadIdx.x;
    int base = blockIdx.x * 1024;
    int cnt = 0;
#pragma unroll
    for (int k2 = 0; k2 < 4; ++k2) cnt += (m[base + k2 * 256 + tid] == 0.0f) ? 1 : 0;
#pragma unroll
    for (int o = 32; o; o >>= 1) cnt += __shfl_xor(cnt, o);
    if ((tid & 63) == 0) sc[tid >> 6] = cnt;
    __syncthreads();
    if (tid == 0) atomicAdd(&accs[1], (double)(sc[0] + sc[1] + sc[2] + sc[3]));
}

// ---------------- K3: GEMM B_j = (2*zf)@cb_j as a single sequential f32 fma chain
// (k-ascending, matching OpenBLAS sgemm), then C_j = fl32(zz - B_j) and argmin
// with FIRST-INDEX tie-break (np.argmin semantics on the quantized scores).
__global__ __launch_bounds__(256) void k_gemm(const float* __restrict__ z,
                                              const float* __restrict__ Bt,
                                              const float* __restrict__ zz,
                                              int* __restrict__ widx,
                                              float* __restrict__ out_idx) {
    __shared__ float lds[64 * AS + 64 * BS];
    float* Als = lds;
    float* Bls = lds + 64 * AS;
    int tid = threadIdx.x;
    int tx = tid & 15, ty = tid >> 4;
    int n0 = blockIdx.x * 64;
    int b = n0 >> 12, hw0 = n0 & 4095;
    const float* zb = z + (size_t)b * CCH * HW + hw0;
    int t16 = tid & 15, td16 = tid >> 4;
    int t32 = tid & 31, td32 = tid >> 5;

    float zzr[4];
#pragma unroll
    for (int i = 0; i < 4; ++i) zzr[i] = zz[n0 + ty * 4 + i];

    float pv[4];
    int pi[4];
#pragma unroll
    for (int i = 0; i < 4; ++i) { pv[i] = 3.0e38f; pi[i] = 0; }

    for (int et = 0; et < 64; ++et) {
        int e0 = et * 128;
        float acc[4][8];
#pragma unroll
        for (int i = 0; i < 4; ++i)
#pragma unroll
            for (int jj = 0; jj < 8; ++jj) acc[i][jj] = 0.0f;

        for (int kc = 0; kc < 8; ++kc) {
            int c0 = kc * 64;
            __syncthreads();
#pragma unroll
            for (int it = 0; it < 4; ++it) {   // A tile: 64n x 64k, scaled by 2 (exact)
                int ck = td16 + it * 16;
                float4 v = *(const float4*)&zb[(size_t)(c0 + ck) * HW + t16 * 4];
                v.x *= 2.0f; v.y *= 2.0f; v.z *= 2.0f; v.w *= 2.0f;
                *(float4*)&Als[ck * AS + t16 * 4] = v;
            }
#pragma unroll
            for (int it = 0; it < 8; ++it) {   // B tile: 128e x 64k (from Bt, k-major)
                int ck = td32 + it * 8;
                float4 v = *(const float4*)&Bt[(size_t)(c0 + ck) * NE + e0 + t32 * 4];
                *(float4*)&Bls[ck * BS + t32 * 4] = v;
            }
            __syncthreads();
#pragma unroll 8
            for (int kk = 0; kk < 64; ++kk) {
                float4 a  = *(const float4*)&Als[kk * AS + ty * 4];
                float4 b0 = *(const float4*)&Bls[kk * BS + tx * 4];
                float4 b1 = *(const float4*)&Bls[kk * BS + 64 + tx * 4];
                acc[0][0] = __fmaf_rn(a.x, b0.x, acc[0][0]);
                acc[0][1] = __fmaf_rn(a.x, b0.y, acc[0][1]);
                acc[0][2] = __fmaf_rn(a.x, b0.z, acc[0][2]);
                acc[0][3] = __fmaf_rn(a.x, b0.w, acc[0][3]);
                acc[0][4] = __fmaf_rn(a.x, b1.x, acc[0][4]);
                acc[0][5] = __fmaf_rn(a.x, b1.y, acc[0][5]);
                acc[0][6] = __fmaf_rn(a.x, b1.z, acc[0][6]);
                acc[0][7] = __fmaf_rn(a.x, b1.w, acc[0][7]);
                acc[1][0] = __fmaf_rn(a.y, b0.x, acc[1][0]);
                acc[1][1] = __fmaf_rn(a.y, b0.y, acc[1][1]);
                acc[1][2] = __fmaf_rn(a.y, b0.z, acc[1][2]);
                acc[1][3] = __fmaf_rn(a.y, b0.w, acc[1][3]);
                acc[1][4] = __fmaf_rn(a.y, b1.x, acc[1][4]);
                acc[1][5] = __fmaf_rn(a.y, b1.y, acc[1][5]);
                acc[1][6] = __fmaf_rn(a.y, b1.z, acc[1][6]);
                acc[1][7] = __fmaf_rn(a.y, b1.w, acc[1][7]);
                acc[2][0] = __fmaf_rn(a.z, b0.x, acc[2][0]);
                acc[2][1] = __fmaf_rn(a.z, b0.y, acc[2][1]);
                acc[2][2] = __fmaf_rn(a.z, b0.z, acc[2][2]);
                acc[2][3] = __fmaf_rn(a.z, b0.w, acc[2][3]);
                acc[2][4] = __fmaf_rn(a.z, b1.x, acc[2][4]);
                acc[2][5] = __fmaf_rn(a.z, b1.y, acc[2][5]);
                acc[2][6] = __fmaf_rn(a.z, b1.z, acc[2][6]);
                acc[2][7] = __fmaf_rn(a.z, b1.w, acc[2][7]);
                acc[3][0] = __fmaf_rn(a.w, b0.x, acc[3][0]);
                acc[3][1] = __fmaf_rn(a.w, b0.y, acc[3][1]);
                acc[3][2] = __fmaf_rn(a.w, b0.z, acc[3][2]);
                acc[3][3] = __fmaf_rn(a.w, b0.w, acc[3][3]);
                acc[3][4] = __fmaf_rn(a.w, b1.x, acc[3][4]);
                acc[3][5] = __fmaf_rn(a.w, b1.y, acc[3][5]);
                acc[3][6] = __fmaf_rn(a.w, b1.z, acc[3][6]);
                acc[3][7] = __fmaf_rn(a.w, b1.w, acc[3][7]);
            }
        }
        // epilogue: C = fl32(zz - B); argmin, first index wins (j ascending per thread)
#pragma unroll
        for (int jj = 0; jj < 8; ++jj) {
            int j = e0 + ((jj < 4) ? (tx * 4 + jj) : (64 + tx * 4 + (jj - 4)));
#pragma unroll
            for (int i = 0; i < 4; ++i) {
                float tt = __fsub_rn(zzr[i], acc[i][jj]);
                if (tt < pv[i]) { pv[i] = tt; pi[i] = j; }
            }
        }
    }

    // cross-thread (tx) reduction per row: smaller value, tie -> smaller index
    __syncthreads();
    float* RV = lds;
    int*   RI = (int*)(lds + 1024);
#pragma unroll
    for (int i = 0; i < 4; ++i) {
        int r = ty * 4 + i;
        RV[r * 16 + tx] = pv[i];
        RI[r * 16 + tx] = pi[i];
    }
    __syncthreads();
    if (tid < 64) {
        float v = RV[tid * 16];
        int i1 = RI[tid * 16];
#pragma unroll
        for (int t = 1; t < 16; ++t) {
            float fv = RV[tid * 16 + t];
            int fi = RI[tid * 16 + t];
            if (fv < v || (fv == v && fi < i1)) { v = fv; i1 = fi; }
        }
        int n = n0 + tid;
        widx[n] = i1;
        out_idx[n] = (float)i1;
    }
}

// ---------------- K4: gather z_q, write z_q_st = zf + (zq - zf), accumulate loss numerator
__global__ __launch_bounds__(256) void k_out(const float* __restrict__ z,
                                             const float* __restrict__ cb,
                                             const float* __restrict__ m,
                                             const int* __restrict__ widx,
                                             float* __restrict__ out0,
                                             double* __restrict__ accs) {
    __shared__ float T[64 * 65];
    __shared__ float ls[4];
    int tid = threadIdx.x;
    int lhw = tid & 63, grp = tid >> 6;
    int bn = blockIdx.x >> 3, bc = blockIdx.x & 7;
    int n0 = bn * 64, c0 = bc * 64;
    int b = n0 >> 12, hw0 = n0 & 4095;
    const float* zb = z + (size_t)b * CCH * HW + hw0;
#pragma unroll
    for (int i = 0; i < 16; ++i) {
        int cl = grp + 4 * i;
        T[cl * 65 + lhw] = zb[(size_t)(c0 + cl) * HW + lhw];
    }
    __syncthreads();
    float la = 0.0f;
#pragma unroll
    for (int i = 0; i < 16; ++i) {
        int nl = grp + 4 * i;
        int n = n0 + nl;
        float zf = T[lhw * 65 + nl];
        int id = widx[n];
        float zq = cb[(size_t)id * CCH + c0 + lhw];
        float d = zq - zf;
        out0[(size_t)n * CCH + c0 + lhw] = zf + d;
        if (m[n] == 0.0f) la = fmaf(d, d, la);
    }
#pragma unroll
    for (int o = 32; o; o >>= 1) la += __shfl_xor(la, o);
    if ((tid & 63) == 0) ls[tid >> 6] = la;
    __syncthreads();
    if (tid == 0) atomicAdd(&accs[0], (double)(ls[0] + ls[1] + ls[2] + ls[3]));
}

// ---------------- K5: finalize loss = (1 + BETA) * mse
__global__ void k_final(const double* __restrict__ accs, float* __restrict__ outl) {
    double num = accs[0], wsum = accs[1];
    double denom = wsum * 512.0;
    double l1 = num / denom;
    outl[0] = (float)(l1 + 0.25 * l1);
}

extern "C" void kernel_launch(void* const* d_in, const int* in_sizes, int n_in,
                              void* d_out, int out_size, void* d_ws, size_t ws_size,
                              hipStream_t stream) {
    const float* z  = (const float*)d_in[0];
    const float* m  = (const float*)d_in[1];
    const float* cb = (const float*)d_in[2];
    float* out = (float*)d_out;
    char* ws = (char*)d_ws;

    float*  Bt   = (float*)(ws + WS_BT);
    float*  zzp  = (float*)(ws + WS_ZZ);
    int*    widx = (int*)(ws + WS_IDX);
    double* accs = (double*)(ws + WS_ACC);

    float* out0    = out;
    float* outLoss = out + 16777216;
    float* outIdx  = out + 16777217;

    hipLaunchKernelGGL(k_transpose, dim3(4096), dim3(256), 0, stream, cb, Bt, accs);
    hipLaunchKernelGGL(k_zz,        dim3(128),  dim3(256), 0, stream, z, zzp);
    hipLaunchKernelGGL(k_wsum,      dim3(32),   dim3(256), 0, stream, m, accs);
    hipLaunchKernelGGL(k_gemm,      dim3(512),  dim3(256), 0, stream, z, Bt, zzp, widx, outIdx);
    hipLaunchKernelGGL(k_out,       dim3(4096), dim3(256), 0, stream, z, cb, m, widx, out0, accs);
    hipLaunchKernelGGL(k_final,     dim3(1),    dim3(1),   0, stream, accs, outLoss);
}